// Round 5
// baseline (273.397 us; speedup 1.0000x reference)
//
#include <hip/hip_runtime.h>
#include <cstdint>
#include <cstddef>

// Problem constants (from reference)
#define B_ 16
#define S_ 24
#define L_ 128
#define D_ 768
#define A_ 8
#define T_ 8
#define NSLOT 24        // 3 arg types (predicate/arg0/arg1) * A
#define HALF_D 384      // each block handles half of D
#define THREADS 192     // 2 row-parities x 96 lanes; 4 dims/thread (float4)
#define QC 96           // lanes per parity
#define CHUNK 8         // rows batched per parity thread (128 B/lane in flight)

__global__ void __launch_bounds__(THREADS)
srl_kernel(const float* __restrict__ emb,            // fp32 [B,S,L,D]
           const int* __restrict__ masks,            // [B,S,L]
           const int* __restrict__ sids,             // [B,S,L]
           const int* __restrict__ pred,             // [B,S,A,T]
           const int* __restrict__ arg0,             // [B,S,A,T]
           const int* __restrict__ arg1,             // [B,S,A,T]
           float* __restrict__ out)                  // fp32: [B,S,D] ++ 3x[B,S,A,D]
{
    const int blk  = blockIdx.x;     // 0..767
    const int bs   = blk >> 1;       // sentence index 0..383
    const int half = blk & 1;        // which D half
    const int tid  = threadIdx.x;
    const int r    = tid / QC;       // row parity 0/1
    const int c    = tid % QC;       // dim quad index: dims [4c, 4c+4)

    __shared__ int          sid_sh[L_];
    __shared__ float        mval_sh[L_];
    __shared__ float        inv_mask_cnt;
    __shared__ int          id_st[NSLOT][T_];
    __shared__ int          cnt_st[NSLOT][T_];
    __shared__ int          chosen_id[NSLOT];
    __shared__ float        inv_cnt[NSLOT];
    __shared__ unsigned int lmask[L_];
    __shared__ float        slot_acc[NSLOT][HALF_D];   // 36 KB
    __shared__ float        pool_sh[QC][4];            // parity merge, 1.5 KB

    // ---- stage sentence ids + mask values ----
    if (tid < L_) {
        sid_sh[tid]  = sids[bs * L_ + tid];
        mval_sh[tid] = (float)masks[bs * L_ + tid];
    }
    __syncthreads();

    // ---- per (slot, t) candidate: id + match count (192 pairs == 192 threads) ----
    {
        const int s24 = tid >> 3;   // 0..23
        const int t   = tid & 7;
        const int g   = s24 >> 3;   // arg type
        const int a   = s24 & 7;
        const int* argp = (g == 0) ? pred : (g == 1) ? arg0 : arg1;
        const int id = argp[((bs * A_) + a) * T_ + t];
        int cnt = 0;
        if (id != 0) {
            #pragma unroll 8
            for (int l = 0; l < L_; ++l) cnt += (sid_sh[l] == id) ? 1 : 0;
        }
        id_st[s24][t]  = id;
        cnt_st[s24][t] = cnt;
    }

    // zero slot accumulators; sync before use below
    {
        float* p = &slot_acc[0][0];
        for (int i = tid; i < NSLOT * HALF_D; i += THREADS) p[i] = 0.0f;
    }
    if (tid == 0) {
        float cm = 0.0f;
        for (int l = 0; l < L_; ++l) cm += mval_sh[l];
        inv_mask_cnt = 1.0f / fmaxf(cm, 1.0f);
    }
    __syncthreads();

    // ---- choose LAST valid t per slot (reference overwrite semantics) ----
    if (tid < NSLOT) {
        int cid = -1;   // sentinel: never equals a sentence id (ids >= 0)
        int ccnt = 0;
        for (int t = T_ - 1; t >= 0; --t) {
            if (cnt_st[tid][t] > 0) { cid = id_st[tid][t]; ccnt = cnt_st[tid][t]; break; }
        }
        chosen_id[tid] = cid;
        inv_cnt[tid]   = (ccnt > 0) ? (1.0f / (float)ccnt) : 0.0f;
    }
    __syncthreads();

    // ---- per-row slot-match bitmask ----
    if (tid < L_) {
        const int s = sid_sh[tid];
        unsigned int m = 0;
        #pragma unroll
        for (int k = 0; k < NSLOT; ++k)
            m |= (unsigned int)(chosen_id[k] == s) << k;
        lmask[tid] = m;
    }
    __syncthreads();

    // ---- main streaming pass: float4/lane, each thread covers rows l = r mod 2 ----
    // rp points at this thread's 4 dims in row r; row step is 2*D.
    const float* rp = emb + (size_t)bs * (L_ * D_) + (size_t)r * D_
                    + half * HALF_D + 4 * c;
    float4 p4 = make_float4(0.f, 0.f, 0.f, 0.f);
    for (int i0 = 0; i0 < L_ / 2; i0 += CHUNK) {
        float4 v[CHUNK];
        #pragma unroll
        for (int j = 0; j < CHUNK; ++j)
            v[j] = *(const float4*)(rp + (size_t)(i0 + j) * (2 * D_));
        #pragma unroll
        for (int j = 0; j < CHUNK; ++j) {
            const int l = r + 2 * (i0 + j);
            const float mk = mval_sh[l];
            p4.x = fmaf(v[j].x, mk, p4.x);
            p4.y = fmaf(v[j].y, mk, p4.y);
            p4.z = fmaf(v[j].z, mk, p4.z);
            p4.w = fmaf(v[j].w, mk, p4.w);
            unsigned int m = lmask[l];        // near-uniform across the wave
            while (m) {
                const int s24 = __ffs(m) - 1;
                m &= m - 1;
                // both parities may hit the same slot dims concurrently -> LDS atomics
                float* ap = &slot_acc[s24][4 * c];
                atomicAdd(ap + 0, v[j].x);
                atomicAdd(ap + 1, v[j].y);
                atomicAdd(ap + 2, v[j].z);
                atomicAdd(ap + 3, v[j].w);
            }
        }
    }

    // ---- merge pool partials across parities ----
    if (r == 1) {
        pool_sh[c][0] = p4.x; pool_sh[c][1] = p4.y;
        pool_sh[c][2] = p4.z; pool_sh[c][3] = p4.w;
    }
    __syncthreads();   // also fences all slot_acc atomics

    // ---- epilogue (fp32 output, float4 stores) ----
    const size_t out0_sz = (size_t)B_ * S_ * D_;
    const size_t arg_sz  = (size_t)B_ * S_ * A_ * D_;
    const int d0 = half * HALF_D + 4 * c;

    if (r == 0) {
        // output 0: mean-pooled sentence embeddings
        float4 o;
        o.x = (p4.x + pool_sh[c][0]) * inv_mask_cnt;
        o.y = (p4.y + pool_sh[c][1]) * inv_mask_cnt;
        o.z = (p4.z + pool_sh[c][2]) * inv_mask_cnt;
        o.w = (p4.w + pool_sh[c][3]) * inv_mask_cnt;
        *(float4*)(out + (size_t)bs * D_ + d0) = o;
    }
    // outputs 1..3: split the 24 slots across the two parities (12 each)
    #pragma unroll
    for (int si = 0; si < NSLOT / 2; ++si) {
        const int s24 = r * (NSLOT / 2) + si;
        const int g = s24 >> 3;
        const int a = s24 & 7;
        const float ic = inv_cnt[s24];        // 0 when no valid token -> exact zeros
        const float* ap = &slot_acc[s24][4 * c];
        float4 o;
        o.x = ap[0] * ic; o.y = ap[1] * ic;
        o.z = ap[2] * ic; o.w = ap[3] * ic;
        float* dst = out + out0_sz + (size_t)g * arg_sz
                   + ((size_t)(bs * A_ + a)) * D_ + d0;
        *(float4*)dst = o;
    }
}

extern "C" void kernel_launch(void* const* d_in, const int* in_sizes, int n_in,
                              void* d_out, int out_size, void* d_ws, size_t ws_size,
                              hipStream_t stream) {
    const float* emb = (const float*)d_in[0];
    const int* masks = (const int*)d_in[1];
    const int* sids  = (const int*)d_in[2];
    const int* pred  = (const int*)d_in[3];
    const int* a0    = (const int*)d_in[4];
    const int* a1    = (const int*)d_in[5];
    float* out = (float*)d_out;

    srl_kernel<<<dim3(2 * B_ * S_), dim3(THREADS), 0, stream>>>(
        emb, masks, sids, pred, a0, a1, out);
}

// Round 6
// 239.143 us; speedup vs baseline: 1.1432x; 1.1432x over previous
//
#include <hip/hip_runtime.h>
#include <cstdint>
#include <cstddef>

// Problem constants (from reference)
#define B_ 16
#define S_ 24
#define L_ 128
#define D_ 768
#define A_ 8
#define T_ 8
#define NSLOT 24              // 3 arg types * A
#define HALF_D 384
#define THREADS 192
#define QC 96                 // quads per D-half
#define CHUNK 8               // rows batched per parity thread
#define POOL_BLOCKS (2 * B_ * S_)          // 768
#define ARG_BLOCKS  (NSLOT * B_ * S_)      // 9216

__global__ void __launch_bounds__(THREADS, 4)
srl_fused(const float* __restrict__ emb,   // fp32 [B,S,L,D]
          const int* __restrict__ masks,   // [B,S,L]
          const int* __restrict__ sids,    // [B,S,L]
          const int* __restrict__ pred,    // [B,S,A,T]
          const int* __restrict__ arg0,
          const int* __restrict__ arg1,
          float* __restrict__ out)         // fp32: [B,S,D] ++ 3x[B,S,A,D]
{
    const int tid = threadIdx.x;
    const size_t out0_sz = (size_t)B_ * S_ * D_;
    const size_t arg_sz  = (size_t)B_ * S_ * A_ * D_;

    if (blockIdx.x < POOL_BLOCKS) {
        // ================= dense mean-pool path =================
        const int blk  = blockIdx.x;
        const int bs   = blk >> 1;
        const int half = blk & 1;
        const int r    = tid / QC;        // row parity
        const int c    = tid % QC;        // dim quad

        __shared__ float mval_sh[L_];
        __shared__ float pool_sh[QC][4];
        __shared__ float inv_sh;

        if (tid < L_) mval_sh[tid] = (float)masks[bs * L_ + tid];
        __syncthreads();

        if (tid < 64) {                    // wave-0 reduction of mask count
            float v = mval_sh[tid] + mval_sh[tid + 64];
            #pragma unroll
            for (int off = 32; off; off >>= 1) v += __shfl_down(v, off, 64);
            if (tid == 0) inv_sh = 1.0f / fmaxf(v, 1.0f);
        }

        const float* rp = emb + (size_t)bs * (L_ * D_) + (size_t)r * D_
                        + half * HALF_D + 4 * c;
        float4 p = make_float4(0.f, 0.f, 0.f, 0.f);
        for (int i0 = 0; i0 < L_ / 2; i0 += CHUNK) {
            float4 v[CHUNK];
            #pragma unroll
            for (int j = 0; j < CHUNK; ++j)
                v[j] = *(const float4*)(rp + (size_t)(i0 + j) * (2 * D_));
            #pragma unroll
            for (int j = 0; j < CHUNK; ++j) {
                const float mk = mval_sh[r + 2 * (i0 + j)];
                p.x = fmaf(v[j].x, mk, p.x);
                p.y = fmaf(v[j].y, mk, p.y);
                p.z = fmaf(v[j].z, mk, p.z);
                p.w = fmaf(v[j].w, mk, p.w);
            }
        }
        if (r == 1) {
            pool_sh[c][0] = p.x; pool_sh[c][1] = p.y;
            pool_sh[c][2] = p.z; pool_sh[c][3] = p.w;
        }
        __syncthreads();
        if (r == 0) {
            const float iv = inv_sh;
            float4 o;
            o.x = (p.x + pool_sh[c][0]) * iv;
            o.y = (p.y + pool_sh[c][1]) * iv;
            o.z = (p.z + pool_sh[c][2]) * iv;
            o.w = (p.w + pool_sh[c][3]) * iv;
            *(float4*)(out + (size_t)bs * D_ + half * HALF_D + 4 * c) = o;
        }
    } else {
        // ================= sparse arg-embedding path =================
        const int task = blockIdx.x - POOL_BLOCKS;   // 0..9215
        const int bs   = task / NSLOT;
        const int slot = task - bs * NSLOT;
        const int g    = slot >> 3;
        const int a    = slot & 7;

        __shared__ int   sid_sh[L_];
        __shared__ int   tok_id[T_];
        __shared__ int   tok_cnt[T_];
        __shared__ int   cid_sh;
        __shared__ float inv_sh2;
        __shared__ int   mlist[L_];
        __shared__ int   mcount;

        if (tid < L_) sid_sh[tid] = sids[bs * L_ + tid];
        if (tid < T_) {
            const int* ap = (g == 0) ? pred : (g == 1) ? arg0 : arg1;
            tok_id[tid]  = ap[(bs * A_ + a) * T_ + tid];
            tok_cnt[tid] = 0;
        }
        if (tid == 0) mcount = 0;
        __syncthreads();

        // count matches per candidate token t (1024 pairs over 192 threads)
        for (int idx = tid; idx < T_ * L_; idx += THREADS) {
            const int t  = idx >> 7;          // /128
            const int l  = idx & (L_ - 1);
            const int id = tok_id[t];
            if (id != 0 && sid_sh[l] == id) atomicAdd(&tok_cnt[t], 1);
        }
        __syncthreads();

        if (tid == 0) {       // last valid t wins (reference overwrite semantics)
            int cid = -1; float iv = 0.f;
            for (int t = T_ - 1; t >= 0; --t)
                if (tok_cnt[t] > 0) { cid = tok_id[t]; iv = 1.0f / (float)tok_cnt[t]; break; }
            cid_sh = cid; inv_sh2 = iv;
        }
        __syncthreads();

        if (tid < L_ && sid_sh[tid] == cid_sh) {
            const int pos = atomicAdd(&mcount, 1);
            mlist[pos] = tid;
        }
        __syncthreads();
        if (tid == 0) {       // tiny insertion sort -> deterministic ascending sum
            const int n = mcount;
            for (int i = 1; i < n; ++i) {
                const int key = mlist[i]; int j = i - 1;
                while (j >= 0 && mlist[j] > key) { mlist[j + 1] = mlist[j]; --j; }
                mlist[j + 1] = key;
            }
        }
        __syncthreads();

        const int n = mcount;                 // uniform
        float4 acc = make_float4(0.f, 0.f, 0.f, 0.f);
        const float* base = emb + (size_t)bs * (L_ * D_) + 4 * tid;
        for (int i = 0; i < n; ++i) {
            const float4 v = *(const float4*)(base + (size_t)mlist[i] * D_);
            acc.x += v.x; acc.y += v.y; acc.z += v.z; acc.w += v.w;
        }
        const float iv = inv_sh2;             // 0 when no valid token -> exact zeros
        float4 o;
        o.x = acc.x * iv; o.y = acc.y * iv; o.z = acc.z * iv; o.w = acc.w * iv;
        float* dst = out + out0_sz + (size_t)g * arg_sz
                   + (size_t)(bs * A_ + a) * D_ + 4 * tid;
        *(float4*)dst = o;
    }
}

extern "C" void kernel_launch(void* const* d_in, const int* in_sizes, int n_in,
                              void* d_out, int out_size, void* d_ws, size_t ws_size,
                              hipStream_t stream) {
    const float* emb = (const float*)d_in[0];
    const int* masks = (const int*)d_in[1];
    const int* sids  = (const int*)d_in[2];
    const int* pred  = (const int*)d_in[3];
    const int* a0    = (const int*)d_in[4];
    const int* a1    = (const int*)d_in[5];
    float* out = (float*)d_out;

    srl_fused<<<dim3(POOL_BLOCKS + ARG_BLOCKS), dim3(THREADS), 0, stream>>>(
        emb, masks, sids, pred, a0, a1, out);
}